// Round 2
// baseline (640.046 us; speedup 1.0000x reference)
//
#include <hip/hip_runtime.h>
#include <hip/hip_bf16.h>
#include <cstdint>

// Problem constants
#define BB 32
#define SS 2048
#define QQ 1024
#define II 1024
#define AA 1024
#define MM (BB * SS)   // 65536 flattened rows

typedef __bf16 bf16x8 __attribute__((ext_vector_type(8)));
typedef float  f32x4  __attribute__((ext_vector_type(4)));

// Pack two fp32 -> two bf16 (round-half-away via +0x8000, then byte-perm). 3 VALU.
__device__ __forceinline__ unsigned int pack_bf2(float a, float b) {
  unsigned ua = __builtin_bit_cast(unsigned, a) + 0x8000u;
  unsigned ub = __builtin_bit_cast(unsigned, b) + 0x8000u;
  return __builtin_amdgcn_perm(ub, ua, 0x07060302u);
}

// async global->LDS, 16B per lane. LDS dest = uniform base + lane*16.
__device__ __forceinline__ void gload_lds16(const void* g, void* l) {
  __builtin_amdgcn_global_load_lds(
      (const __attribute__((address_space(1))) void*)g,
      (__attribute__((address_space(3))) void*)l, 16, 0, 0);
}

// ---------------- U transpose+convert: Ut[n][k] = bf16(U[k][n]) ----------------
__global__ void __launch_bounds__(256) k_transpose_u(const float* __restrict__ U,
                                                     unsigned short* __restrict__ Ut) {
  __shared__ float t[64][65];
  const int n0 = blockIdx.x * 64, k0 = blockIdx.y * 64;
  const int c = threadIdx.x & 63, r0 = threadIdx.x >> 6;
#pragma unroll
  for (int r = r0; r < 64; r += 4) t[r][c] = U[(size_t)(k0 + r) * AA + n0 + c];
  __syncthreads();
#pragma unroll
  for (int r = r0; r < 64; r += 4) {
    __hip_bfloat16 h = __float2bfloat16(t[c][r]);
    Ut[(size_t)(n0 + r) * II + k0 + c] = __builtin_bit_cast(unsigned short, h);
  }
}

// ---------------- items fp32 -> bf16 (row-major, k-contiguous) ----------------
__global__ void __launch_bounds__(256) k_conv(const float* __restrict__ in,
                                              uint4* __restrict__ outbf) {
  const size_t n8 = (size_t)MM * II / 8;   // 8 elems per slot
  const size_t stride = (size_t)gridDim.x * 256;
  for (size_t i = (size_t)blockIdx.x * 256 + threadIdx.x; i < n8; i += stride) {
    const float4* p = (const float4*)(in + i * 8);
    float4 a = p[0], b = p[1];
    uint4 w;
    w.x = pack_bf2(a.x, a.y); w.y = pack_bf2(a.z, a.w);
    w.z = pack_bf2(b.x, b.y); w.w = pack_bf2(b.z, b.w);
    outbf[i] = w;
  }
}

// ---------------- pq[b][a] = sum_q queries[b][q] * W[q][a] ----------------
__global__ void __launch_bounds__(128) k_pq(const float* __restrict__ q,
                                            const float* __restrict__ W,
                                            float* __restrict__ pq) {
  const int a  = blockIdx.x * 128 + threadIdx.x;
  const int b  = blockIdx.y;
  const int q0 = blockIdx.z * 256;
  const float* qr = q + b * QQ + q0;
  const float* Wp = W + (size_t)q0 * AA + a;
  float acc = 0.f;
#pragma unroll 8
  for (int i = 0; i < 256; ++i) acc += qr[i] * Wp[(size_t)i * AA];
  atomicAdd(&pq[b * AA + a], acc);
}

// Shared epilogue: x=acc+pq; tanh; *v; 16-col butterfly reduce; atomic into react.
__device__ __forceinline__ void react_epilogue(f32x4 (&acc)[4][4], const float* pq,
                                               const float* v, float* react,
                                               int b, int m0, int n0, int wm, int wn,
                                               int quad, int sx) {
  float pqv[4], vv[4];
#pragma unroll
  for (int ni = 0; ni < 4; ++ni) {
    const int n = n0 + wn * 64 + ni * 16 + sx;
    pqv[ni] = pq[b * AA + n];
    vv[ni]  = v[n];
  }
#pragma unroll
  for (int mi = 0; mi < 4; ++mi) {
#pragma unroll
    for (int reg = 0; reg < 4; ++reg) {
      float ssum = 0.f;
#pragma unroll
      for (int ni = 0; ni < 4; ++ni) {
        const float x = acc[mi][ni][reg] + pqv[ni];
        const float e = __expf(2.f * x);
        const float t = 1.f - 2.f * __builtin_amdgcn_rcpf(e + 1.f);  // tanh(x)
        ssum += t * vv[ni];
      }
      ssum += __shfl_xor(ssum, 1);
      ssum += __shfl_xor(ssum, 2);
      ssum += __shfl_xor(ssum, 4);
      ssum += __shfl_xor(ssum, 8);
      if (sx == 0) {
        const int m = m0 + wm * 64 + mi * 16 + quad * 4 + reg;
        atomicAdd(&react[m], ssum);
      }
    }
  }
}

// ---------------- PATH A: bf16 A + global_load_lds both operands (m97 structure) ----
__global__ void __launch_bounds__(256) k_gemm_bf(const unsigned short* __restrict__ Abf,
                                                 const unsigned short* __restrict__ Ut,
                                                 const float* __restrict__ pq,
                                                 const float* __restrict__ v,
                                                 float* __restrict__ react) {
  // LDS slot (r, c) holds global k-chunk (c ^ (r&7)); swizzle applied on the
  // GLOBAL address side so the LDS side stays lane-contiguous (global_load_lds
  // requires dest = uniform base + lane*16). Frag reads: <=2-way conflicts (measured 0).
  __shared__ unsigned short As[128 * 64];
  __shared__ unsigned short Bs[128 * 64];

  const int tid  = threadIdx.x;
  const int lane = tid & 63, wid = tid >> 6;
  const int wm = wid >> 1, wn = wid & 1;
  const int quad = lane >> 4, sx = lane & 15;

  const unsigned id = blockIdx.x;
  const int xcd = id & 7;
  const int j   = id >> 3;
  const int mtile = xcd + 8 * (j >> 3);
  const int ntile = j & 7;
  const int m0 = mtile * 128, n0 = ntile * 128;
  const int b  = m0 >> 11;

  // staging map: lane -> (row-in-8-group, chunk)
  const int r_loc = lane >> 3;        // 0..7
  const int cch   = lane & 7;         // 0..7
  const int gch   = cch ^ r_loc;      // global k-chunk for this lane (swizzle)

  f32x4 acc[4][4] = {};

  for (int kk = 0; kk < 16; ++kk) {
    const int k0 = kk * 64;
    __syncthreads();
#pragma unroll
    for (int jj = 0; jj < 4; ++jj) {
      const int rA = wid * 32 + jj * 8 + r_loc;   // wave-uniform base row + lane row
      gload_lds16(Abf + (size_t)(m0 + rA) * II + k0 + gch * 8,
                  &As[(wid * 32 + jj * 8) * 64]);
    }
#pragma unroll
    for (int jj = 0; jj < 4; ++jj) {
      const int rB = wid * 32 + jj * 8 + r_loc;
      gload_lds16(Ut + (size_t)(n0 + rB) * II + k0 + gch * 8,
                  &Bs[(wid * 32 + jj * 8) * 64]);
    }
    __syncthreads();
#pragma unroll
    for (int ks = 0; ks < 2; ++ks) {
      bf16x8 af[4], bfv[4];
#pragma unroll
      for (int mi = 0; mi < 4; ++mi) {
        const int r = wm * 64 + mi * 16 + sx;
        const int c = (ks * 4 + quad) ^ (r & 7);
        af[mi] = *(const bf16x8*)&As[r * 64 + c * 8];
      }
#pragma unroll
      for (int ni = 0; ni < 4; ++ni) {
        const int r = wn * 64 + ni * 16 + sx;
        const int c = (ks * 4 + quad) ^ (r & 7);
        bfv[ni] = *(const bf16x8*)&Bs[r * 64 + c * 8];
      }
#pragma unroll
      for (int mi = 0; mi < 4; ++mi)
#pragma unroll
        for (int ni = 0; ni < 4; ++ni)
          acc[mi][ni] = __builtin_amdgcn_mfma_f32_16x16x32_bf16(af[mi], bfv[ni], acc[mi][ni], 0, 0, 0);
    }
  }
  react_epilogue(acc, pq, v, react, b, m0, n0, wm, wn, quad, sx);
}

// ---------------- PATH B (fallback, ws too small): in-kernel fp32->bf16 staging ----
__global__ void __launch_bounds__(256) k_gemm_f32(const float* __restrict__ items,
                                                  const unsigned short* __restrict__ Ut,
                                                  const float* __restrict__ pq,
                                                  const float* __restrict__ v,
                                                  float* __restrict__ react) {
  __shared__ unsigned short As[128 * 64];
  __shared__ unsigned short Bs[128 * 64];
  const int tid  = threadIdx.x;
  const int lane = tid & 63, wid = tid >> 6;
  const int wm = wid >> 1, wn = wid & 1;
  const int quad = lane >> 4, sx = lane & 15;
  const unsigned id = blockIdx.x;
  const int xcd = id & 7;
  const int j   = id >> 3;
  const int mtile = xcd + 8 * (j >> 3);
  const int ntile = j & 7;
  const int m0 = mtile * 128, n0 = ntile * 128;
  const int b  = m0 >> 11;
  const int ar = tid >> 2, aq = tid & 3;
  const int bn = tid >> 1, bh = tid & 1;
  f32x4 acc[4][4] = {};
  for (int kk = 0; kk < 16; ++kk) {
    const int k0 = kk * 64;
    __syncthreads();
#pragma unroll
    for (int rr = 0; rr < 2; ++rr) {
      const int r = ar + rr * 64;
      const float* g = items + (size_t)(m0 + r) * II + k0 + aq * 16;
      float4 f0 = ((const float4*)g)[0];
      float4 f1 = ((const float4*)g)[1];
      float4 f2 = ((const float4*)g)[2];
      float4 f3 = ((const float4*)g)[3];
      uint4 w0, w1;
      w0.x = pack_bf2(f0.x, f0.y); w0.y = pack_bf2(f0.z, f0.w);
      w0.z = pack_bf2(f1.x, f1.y); w0.w = pack_bf2(f1.z, f1.w);
      w1.x = pack_bf2(f2.x, f2.y); w1.y = pack_bf2(f2.z, f2.w);
      w1.z = pack_bf2(f3.x, f3.y); w1.w = pack_bf2(f3.z, f3.w);
      const int c0 = (2 * aq) ^ (r & 7);
      const int c1 = (2 * aq + 1) ^ (r & 7);
      *(uint4*)&As[r * 64 + c0 * 8] = w0;
      *(uint4*)&As[r * 64 + c1 * 8] = w1;
    }
    {
      const unsigned short* g = Ut + (size_t)(n0 + bn) * II + k0 + bh * 32;
#pragma unroll
      for (int jj = 0; jj < 4; ++jj) {
        uint4 w = ((const uint4*)g)[jj];
        const int c = (bh * 4 + jj) ^ (bn & 7);
        *(uint4*)&Bs[bn * 64 + c * 8] = w;
      }
    }
    __syncthreads();
#pragma unroll
    for (int ks = 0; ks < 2; ++ks) {
      bf16x8 af[4], bfv[4];
#pragma unroll
      for (int mi = 0; mi < 4; ++mi) {
        const int r = wm * 64 + mi * 16 + sx;
        const int c = (ks * 4 + quad) ^ (r & 7);
        af[mi] = *(const bf16x8*)&As[r * 64 + c * 8];
      }
#pragma unroll
      for (int ni = 0; ni < 4; ++ni) {
        const int r = wn * 64 + ni * 16 + sx;
        const int c = (ks * 4 + quad) ^ (r & 7);
        bfv[ni] = *(const bf16x8*)&Bs[r * 64 + c * 8];
      }
#pragma unroll
      for (int mi = 0; mi < 4; ++mi)
#pragma unroll
        for (int ni = 0; ni < 4; ++ni)
          acc[mi][ni] = __builtin_amdgcn_mfma_f32_16x16x32_bf16(af[mi], bfv[ni], acc[mi][ni], 0, 0, 0);
    }
  }
  react_epilogue(acc, pq, v, react, b, m0, n0, wm, wn, quad, sx);
}

// ---------------- masked softmax over S per batch ----------------
__global__ void __launch_bounds__(256) k_softmax(const float* __restrict__ react,
                                                 const int* __restrict__ weights,
                                                 float* __restrict__ scores) {
  const int b = blockIdx.x, tid = threadIdx.x;
  const int lane = tid & 63, wid = tid >> 6;
  __shared__ float redm[4], reds[4];
  float vals[8];
  float mx = -3.0e38f;
#pragma unroll
  for (int j = 0; j < 8; ++j) {
    const int s = j * 256 + tid;
    const float r = react[b * SS + s];
    const int w = weights[b * SS + s];
    const float val = (w != 0) ? r : -3.0e38f;
    vals[j] = val;
    mx = fmaxf(mx, val);
  }
#pragma unroll
  for (int off = 1; off < 64; off <<= 1) mx = fmaxf(mx, __shfl_xor(mx, off));
  if (lane == 0) redm[wid] = mx;
  __syncthreads();
  mx = fmaxf(fmaxf(redm[0], redm[1]), fmaxf(redm[2], redm[3]));
  float e[8], sum = 0.f;
#pragma unroll
  for (int j = 0; j < 8; ++j) {
    e[j] = (vals[j] < -1.0e38f) ? 0.f : __expf(vals[j] - mx);
    sum += e[j];
  }
#pragma unroll
  for (int off = 1; off < 64; off <<= 1) sum += __shfl_xor(sum, off);
  if (lane == 0) reds[wid] = sum;
  __syncthreads();
  const float inv = 1.f / (reds[0] + reds[1] + reds[2] + reds[3]);
#pragma unroll
  for (int j = 0; j < 8; ++j) scores[b * SS + j * 256 + tid] = e[j] * inv;
}

// ---------------- blended: block-local compaction + branch-free x4 loop ----------------
// grid (BB, 16): each block owns 128 s-rows of one batch; i covered by 256 thr x float4.
__global__ void __launch_bounds__(256) k_blended(const float* __restrict__ items,
                                                 const float* __restrict__ scores,
                                                 float* __restrict__ out) {
  const int b = blockIdx.x, chunk = blockIdx.y, tid = threadIdx.x;
  __shared__ int   lidx[132];
  __shared__ float lsc[132];
  __shared__ int   lcount;
  if (tid == 0) lcount = 0;
  __syncthreads();
  if (tid < 128) {
    const int s = chunk * 128 + tid;
    const float sc = scores[b * SS + s];
    if (sc != 0.f) {                       // masked rows are exact zeros
      const int p = atomicAdd(&lcount, 1);
      lidx[p] = s; lsc[p] = sc;
    }
  }
  __syncthreads();
  const int cnt = lcount;
  if (tid < 4) {                           // pad to multiple of 4 with zero-weight dummies
    const int p = cnt + tid;
    if (p < 132) { lidx[p] = chunk * 128; lsc[p] = 0.f; }
  }
  __syncthreads();
  const int cnt4 = (cnt + 3) & ~3;
  const float4* base = (const float4*)(items + (size_t)b * SS * II);
  float4 acc = {0.f, 0.f, 0.f, 0.f};
  for (int j0 = 0; j0 < cnt4; j0 += 4) {
    const int   s0 = lidx[j0],   s1 = lidx[j0+1], s2 = lidx[j0+2], s3 = lidx[j0+3];
    const float w0 = lsc[j0],    w1 = lsc[j0+1],  w2 = lsc[j0+2],  w3 = lsc[j0+3];
    const float4 x0 = base[(size_t)s0 * 256 + tid];
    const float4 x1 = base[(size_t)s1 * 256 + tid];
    const float4 x2 = base[(size_t)s2 * 256 + tid];
    const float4 x3 = base[(size_t)s3 * 256 + tid];
    acc.x += w0*x0.x + w1*x1.x + w2*x2.x + w3*x3.x;
    acc.y += w0*x0.y + w1*x1.y + w2*x2.y + w3*x3.y;
    acc.z += w0*x0.z + w1*x1.z + w2*x2.z + w3*x3.z;
    acc.w += w0*x0.w + w1*x1.w + w2*x2.w + w3*x3.w;
  }
  float* o = out + b * II + tid * 4;
  atomicAdd(o + 0, acc.x);
  atomicAdd(o + 1, acc.y);
  atomicAdd(o + 2, acc.z);
  atomicAdd(o + 3, acc.w);
}

extern "C" void kernel_launch(void* const* d_in, const int* in_sizes, int n_in,
                              void* d_out, int out_size, void* d_ws, size_t ws_size,
                              hipStream_t stream) {
  const float* queries = (const float*)d_in[0];
  const float* items   = (const float*)d_in[1];
  const int*   weights = (const int*)d_in[2];
  const float* W       = (const float*)d_in[3];
  const float* U       = (const float*)d_in[4];
  const float* v       = (const float*)d_in[5];
  float* out = (float*)d_out;

  char* ws = (char*)d_ws;
  unsigned short* Ut = (unsigned short*)ws;                         // 2 MB
  float* pq    = (float*)(ws + (2u << 20));                         // 128 KB
  float* react = (float*)(ws + (2u << 20) + (128u << 10));          // 256 KB
  const size_t bf_off = (2u << 20) + (128u << 10) + (256u << 10);   // 16B-aligned
  unsigned short* Abf = (unsigned short*)(ws + bf_off);             // 128 MB (path A)
  const bool pathA = ws_size >= bf_off + (size_t)MM * II * 2;

  hipMemsetAsync(pq, 0, BB * AA * sizeof(float), stream);
  hipMemsetAsync(react, 0, MM * sizeof(float), stream);
  hipMemsetAsync(out, 0, BB * II * sizeof(float), stream);

  k_transpose_u<<<dim3(16, 16), 256, 0, stream>>>(U, Ut);
  k_pq<<<dim3(8, BB, 4), 128, 0, stream>>>(queries, W, pq);
  if (pathA) {
    k_conv<<<dim3(16384), 256, 0, stream>>>(items, (uint4*)Abf);
    k_gemm_bf<<<dim3(4096), 256, 0, stream>>>(Abf, Ut, pq, v, react);
  } else {
    k_gemm_f32<<<dim3(4096), 256, 0, stream>>>(items, Ut, pq, v, react);
  }
  k_softmax<<<dim3(BB), 256, 0, stream>>>(react, weights, out + BB * II);
  k_blended<<<dim3(BB, 16), 256, 0, stream>>>(items, out + BB * II, out);
}

// Round 3
// 611.270 us; speedup vs baseline: 1.0471x; 1.0471x over previous
//
#include <hip/hip_runtime.h>
#include <hip/hip_bf16.h>
#include <cstdint>

// Problem constants
#define BB 32
#define SS 2048
#define QQ 1024
#define II 1024
#define AA 1024
#define MM (BB * SS)   // 65536 flattened rows

typedef __bf16 bf16x8 __attribute__((ext_vector_type(8)));
typedef float  f32x4  __attribute__((ext_vector_type(4)));

// Pack two fp32 -> two bf16 (round-half-away via +0x8000, then byte-perm).
__device__ __forceinline__ unsigned int pack_bf2(float a, float b) {
  unsigned ua = __builtin_bit_cast(unsigned, a) + 0x8000u;
  unsigned ub = __builtin_bit_cast(unsigned, b) + 0x8000u;
  return __builtin_amdgcn_perm(ub, ua, 0x07060302u);  // lo=bf16(a), hi=bf16(b)
}

// async global->LDS, 16B per lane. LDS dest = uniform base + lane*16.
__device__ __forceinline__ void gload_lds16(const void* g, void* l) {
  __builtin_amdgcn_global_load_lds(
      (const __attribute__((address_space(1))) void*)g,
      (__attribute__((address_space(3))) void*)l, 16, 0, 0);
}

// ---------------- U transpose+convert: Ut[n][k] = bf16(U[k][n]) ----------------
__global__ void __launch_bounds__(256) k_transpose_u(const float* __restrict__ U,
                                                     unsigned short* __restrict__ Ut) {
  __shared__ float t[64][65];
  const int n0 = blockIdx.x * 64, k0 = blockIdx.y * 64;
  const int c = threadIdx.x & 63, r0 = threadIdx.x >> 6;
#pragma unroll
  for (int r = r0; r < 64; r += 4) t[r][c] = U[(size_t)(k0 + r) * AA + n0 + c];
  __syncthreads();
#pragma unroll
  for (int r = r0; r < 64; r += 4) {
    __hip_bfloat16 h = __float2bfloat16(t[c][r]);
    Ut[(size_t)(n0 + r) * II + k0 + c] = __builtin_bit_cast(unsigned short, h);
  }
}

// ---------------- items fp32 -> bf16, PRE-SWIZZLED into MFMA A-fragment order ----
// Element (m,k) -> 16B slot ((m>>4)*32 + (k>>5))*64 + lane, lane = ((k>>3)&3)*16 + (m&15),
// byte (k&7)*2. A wave's 16x16x32 A-frag read = one coalesced global_load_dwordx4.
// Block = one 16-row m-strip (64KB in, 32KB out), staged via LDS for coalescing.
__global__ void __launch_bounds__(256) k_conv_swz(const float* __restrict__ in,
                                                  unsigned short* __restrict__ Aswz) {
  __shared__ unsigned short swz[16 * 1024];   // 32KB, indexed by 8B groups [e4]
  const int mt = blockIdx.x, tid = threadIdx.x;
  const float4* src = (const float4*)(in + (size_t)mt * 16 * 1024);
  // phase 1: coalesced read + convert; store linear by e4 (8B per thread-iter)
#pragma unroll
  for (int i = 0; i < 16; ++i) {
    const int e4 = i * 256 + tid;            // float4 index in strip
    float4 f = src[e4];
    uint2 h;
    h.x = pack_bf2(f.x, f.y);
    h.y = pack_bf2(f.z, f.w);
    *(uint2*)&swz[e4 * 4] = h;
  }
  __syncthreads();
  // phase 2: gather swizzled 16B slots, stream out coalesced
  uint4* dst = (uint4*)Aswz + (size_t)mt * 2048;   // 2048 slots per strip
#pragma unroll
  for (int i = 0; i < 8; ++i) {
    const int s = i * 256 + tid;             // slot index in strip
    const int m = s & 15;
    const int lf = s & 63;                   // lane field
    const int quadk = lf >> 4;
    const int kc = s >> 6;
    const int e4b = m * 256 + kc * 8 + quadk * 2;   // two 8B groups (k..k+3, k+4..k+7)
    uint2 lo = *(const uint2*)&swz[e4b * 4];
    uint2 hi = *(const uint2*)&swz[(e4b + 1) * 4];
    uint4 w; w.x = lo.x; w.y = lo.y; w.z = hi.x; w.w = hi.y;
    dst[s] = w;
  }
}

// ---------------- pq[b][a] = sum_q queries[b][q] * W[q][a] (W read exactly once) ----
__global__ void __launch_bounds__(256) k_pq(const float* __restrict__ q,
                                            const float* __restrict__ W,
                                            float* __restrict__ pq) {
  __shared__ float qs[32 * 256];             // all 32 batches' q-chunk
  const int ab = blockIdx.x, qc = blockIdx.y, tid = threadIdx.x;
#pragma unroll
  for (int j = 0; j < 32; ++j) qs[j * 256 + tid] = q[j * QQ + qc * 256 + tid];
  __syncthreads();
  const int a  = ab * 128 + (tid & 127);
  const int bg = tid >> 7;                   // 0..1 -> batches bg*16..bg*16+15
  float acc[16] = {};
  const float* Wp = W + (size_t)(qc * 256) * AA + a;
  for (int i = 0; i < 256; ++i) {
    const float w = Wp[(size_t)i * AA];
#pragma unroll
    for (int bb = 0; bb < 16; ++bb) acc[bb] += w * qs[(bg * 16 + bb) * 256 + i];
  }
#pragma unroll
  for (int bb = 0; bb < 16; ++bb) atomicAdd(&pq[(bg * 16 + bb) * AA + a], acc[bb]);
}

// Shared epilogue: x=acc+pq; tanh; *v; 16-col butterfly reduce; atomic into react.
__device__ __forceinline__ void react_epilogue(f32x4 (&acc)[4][4], const float* pq,
                                               const float* v, float* react,
                                               int b, int m0, int n0, int wm, int wn,
                                               int quad, int sx) {
  float pqv[4], vv[4];
#pragma unroll
  for (int ni = 0; ni < 4; ++ni) {
    const int n = n0 + wn * 64 + ni * 16 + sx;
    pqv[ni] = pq[b * AA + n];
    vv[ni]  = v[n];
  }
#pragma unroll
  for (int mi = 0; mi < 4; ++mi) {
#pragma unroll
    for (int reg = 0; reg < 4; ++reg) {
      float ssum = 0.f;
#pragma unroll
      for (int ni = 0; ni < 4; ++ni) {
        const float x = acc[mi][ni][reg] + pqv[ni];
        const float e = __expf(2.f * x);
        const float t = 1.f - 2.f * __builtin_amdgcn_rcpf(e + 1.f);  // tanh(x)
        ssum += t * vv[ni];
      }
      ssum += __shfl_xor(ssum, 1);
      ssum += __shfl_xor(ssum, 2);
      ssum += __shfl_xor(ssum, 4);
      ssum += __shfl_xor(ssum, 8);
      if (sx == 0) {
        const int m = m0 + wm * 64 + mi * 16 + quad * 4 + reg;
        atomicAdd(&react[m], ssum);
      }
    }
  }
}

// ---------------- PATH A: A-frags direct from pre-swizzled global; B via LDS ----
__global__ void __launch_bounds__(256, 3) k_gemm_bf(const unsigned short* __restrict__ Aswz,
                                                    const unsigned short* __restrict__ Ut,
                                                    const float* __restrict__ pq,
                                                    const float* __restrict__ v,
                                                    float* __restrict__ react) {
  __shared__ unsigned short Bs[128 * 64];   // 16KB only

  const int tid  = threadIdx.x;
  const int lane = tid & 63, wid = tid >> 6;
  const int wm = wid >> 1, wn = wid & 1;
  const int quad = lane >> 4, sx = lane & 15;

  const unsigned id = blockIdx.x;
  const int xcd = id & 7;
  const int j   = id >> 3;
  const int mtile = xcd + 8 * (j >> 3);
  const int ntile = j & 7;
  const int m0 = mtile * 128, n0 = ntile * 128;
  const int b  = m0 >> 11;

  // B staging map (global-side swizzle; LDS stays lane-contiguous for global_load_lds)
  const int r_loc = lane >> 3;
  const int cch   = lane & 7;
  const int gch   = cch ^ r_loc;

  // A fragment base: slot = ((m16b+mi)*32 + g)*64 + lane
  const bf16x8* Ab = (const bf16x8*)Aswz;
  const int m16b = (m0 + wm * 64) >> 4;

  f32x4 acc[4][4] = {};

  for (int kk = 0; kk < 16; ++kk) {
    const int k0 = kk * 64;
    __syncthreads();                           // Bs consumed
    // ---- B: global->LDS async, 16B ----
#pragma unroll
    for (int jj = 0; jj < 4; ++jj) {
      const int rB = wid * 32 + jj * 8 + r_loc;
      gload_lds16(Ut + (size_t)(n0 + rB) * II + k0 + gch * 8,
                  &Bs[(wid * 32 + jj * 8) * 64]);
    }
    // ---- A: direct fragment loads (drain together with B at the barrier) ----
    bf16x8 af[2][4];
#pragma unroll
    for (int ks = 0; ks < 2; ++ks) {
      const int g = kk * 2 + ks;
#pragma unroll
      for (int mi = 0; mi < 4; ++mi)
        af[ks][mi] = Ab[(size_t)((m16b + mi) * 32 + g) * 64 + lane];
    }
    __syncthreads();                           // A regs + Bs ready
#pragma unroll
    for (int ks = 0; ks < 2; ++ks) {
      bf16x8 bfv[4];
#pragma unroll
      for (int ni = 0; ni < 4; ++ni) {
        const int r = wn * 64 + ni * 16 + sx;
        const int c = (ks * 4 + quad) ^ (r & 7);
        bfv[ni] = *(const bf16x8*)&Bs[r * 64 + c * 8];
      }
#pragma unroll
      for (int mi = 0; mi < 4; ++mi)
#pragma unroll
        for (int ni = 0; ni < 4; ++ni)
          acc[mi][ni] = __builtin_amdgcn_mfma_f32_16x16x32_bf16(af[ks][mi], bfv[ni], acc[mi][ni], 0, 0, 0);
    }
  }
  react_epilogue(acc, pq, v, react, b, m0, n0, wm, wn, quad, sx);
}

// ---------------- PATH B (fallback, ws too small): in-kernel fp32->bf16 staging ----
__global__ void __launch_bounds__(256) k_gemm_f32(const float* __restrict__ items,
                                                  const unsigned short* __restrict__ Ut,
                                                  const float* __restrict__ pq,
                                                  const float* __restrict__ v,
                                                  float* __restrict__ react) {
  __shared__ unsigned short As[128 * 64];
  __shared__ unsigned short Bs[128 * 64];
  const int tid  = threadIdx.x;
  const int lane = tid & 63, wid = tid >> 6;
  const int wm = wid >> 1, wn = wid & 1;
  const int quad = lane >> 4, sx = lane & 15;
  const unsigned id = blockIdx.x;
  const int xcd = id & 7;
  const int j   = id >> 3;
  const int mtile = xcd + 8 * (j >> 3);
  const int ntile = j & 7;
  const int m0 = mtile * 128, n0 = ntile * 128;
  const int b  = m0 >> 11;
  const int ar = tid >> 2, aq = tid & 3;
  const int bn = tid >> 1, bh = tid & 1;
  f32x4 acc[4][4] = {};
  for (int kk = 0; kk < 16; ++kk) {
    const int k0 = kk * 64;
    __syncthreads();
#pragma unroll
    for (int rr = 0; rr < 2; ++rr) {
      const int r = ar + rr * 64;
      const float* g = items + (size_t)(m0 + r) * II + k0 + aq * 16;
      float4 f0 = ((const float4*)g)[0];
      float4 f1 = ((const float4*)g)[1];
      float4 f2 = ((const float4*)g)[2];
      float4 f3 = ((const float4*)g)[3];
      uint4 w0, w1;
      w0.x = pack_bf2(f0.x, f0.y); w0.y = pack_bf2(f0.z, f0.w);
      w0.z = pack_bf2(f1.x, f1.y); w0.w = pack_bf2(f1.z, f1.w);
      w1.x = pack_bf2(f2.x, f2.y); w1.y = pack_bf2(f2.z, f2.w);
      w1.z = pack_bf2(f3.x, f3.y); w1.w = pack_bf2(f3.z, f3.w);
      const int c0 = (2 * aq) ^ (r & 7);
      const int c1 = (2 * aq + 1) ^ (r & 7);
      *(uint4*)&As[r * 64 + c0 * 8] = w0;
      *(uint4*)&As[r * 64 + c1 * 8] = w1;
    }
    {
      const unsigned short* g = Ut + (size_t)(n0 + bn) * II + k0 + bh * 32;
#pragma unroll
      for (int jj = 0; jj < 4; ++jj) {
        uint4 w = ((const uint4*)g)[jj];
        const int c = (bh * 4 + jj) ^ (bn & 7);
        *(uint4*)&Bs[bn * 64 + c * 8] = w;
      }
    }
    __syncthreads();
#pragma unroll
    for (int ks = 0; ks < 2; ++ks) {
      bf16x8 af[4], bfv[4];
#pragma unroll
      for (int mi = 0; mi < 4; ++mi) {
        const int r = wm * 64 + mi * 16 + sx;
        const int c = (ks * 4 + quad) ^ (r & 7);
        af[mi] = *(const bf16x8*)&As[r * 64 + c * 8];
      }
#pragma unroll
      for (int ni = 0; ni < 4; ++ni) {
        const int r = wn * 64 + ni * 16 + sx;
        const int c = (ks * 4 + quad) ^ (r & 7);
        bfv[ni] = *(const bf16x8*)&Bs[r * 64 + c * 8];
      }
#pragma unroll
      for (int mi = 0; mi < 4; ++mi)
#pragma unroll
        for (int ni = 0; ni < 4; ++ni)
          acc[mi][ni] = __builtin_amdgcn_mfma_f32_16x16x32_bf16(af[mi], bfv[ni], acc[mi][ni], 0, 0, 0);
    }
  }
  react_epilogue(acc, pq, v, react, b, m0, n0, wm, wn, quad, sx);
}

// ---------------- masked softmax over S per batch ----------------
__global__ void __launch_bounds__(256) k_softmax(const float* __restrict__ react,
                                                 const int* __restrict__ weights,
                                                 float* __restrict__ scores) {
  const int b = blockIdx.x, tid = threadIdx.x;
  const int lane = tid & 63, wid = tid >> 6;
  __shared__ float redm[4], reds[4];
  float vals[8];
  float mx = -3.0e38f;
#pragma unroll
  for (int j = 0; j < 8; ++j) {
    const int s = j * 256 + tid;
    const float r = react[b * SS + s];
    const int w = weights[b * SS + s];
    const float val = (w != 0) ? r : -3.0e38f;
    vals[j] = val;
    mx = fmaxf(mx, val);
  }
#pragma unroll
  for (int off = 1; off < 64; off <<= 1) mx = fmaxf(mx, __shfl_xor(mx, off));
  if (lane == 0) redm[wid] = mx;
  __syncthreads();
  mx = fmaxf(fmaxf(redm[0], redm[1]), fmaxf(redm[2], redm[3]));
  float e[8], sum = 0.f;
#pragma unroll
  for (int j = 0; j < 8; ++j) {
    e[j] = (vals[j] < -1.0e38f) ? 0.f : __expf(vals[j] - mx);
    sum += e[j];
  }
#pragma unroll
  for (int off = 1; off < 64; off <<= 1) sum += __shfl_xor(sum, off);
  if (lane == 0) reds[wid] = sum;
  __syncthreads();
  const float inv = 1.f / (reds[0] + reds[1] + reds[2] + reds[3]);
#pragma unroll
  for (int j = 0; j < 8; ++j) scores[b * SS + j * 256 + tid] = e[j] * inv;
}

// ---------------- blended: block-local compaction + branch-free x4 loop ----------------
__global__ void __launch_bounds__(256) k_blended(const float* __restrict__ items,
                                                 const float* __restrict__ scores,
                                                 float* __restrict__ out) {
  const int b = blockIdx.x, chunk = blockIdx.y, tid = threadIdx.x;
  __shared__ int   lidx[132];
  __shared__ float lsc[132];
  __shared__ int   lcount;
  if (tid == 0) lcount = 0;
  __syncthreads();
  if (tid < 128) {
    const int s = chunk * 128 + tid;
    const float sc = scores[b * SS + s];
    if (sc != 0.f) {
      const int p = atomicAdd(&lcount, 1);
      lidx[p] = s; lsc[p] = sc;
    }
  }
  __syncthreads();
  const int cnt = lcount;
  if (tid < 4) {
    const int p = cnt + tid;
    if (p < 132) { lidx[p] = chunk * 128; lsc[p] = 0.f; }
  }
  __syncthreads();
  const int cnt4 = (cnt + 3) & ~3;
  const float4* base = (const float4*)(items + (size_t)b * SS * II);
  float4 acc = {0.f, 0.f, 0.f, 0.f};
  for (int j0 = 0; j0 < cnt4; j0 += 4) {
    const int   s0 = lidx[j0],   s1 = lidx[j0+1], s2 = lidx[j0+2], s3 = lidx[j0+3];
    const float w0 = lsc[j0],    w1 = lsc[j0+1],  w2 = lsc[j0+2],  w3 = lsc[j0+3];
    const float4 x0 = base[(size_t)s0 * 256 + tid];
    const float4 x1 = base[(size_t)s1 * 256 + tid];
    const float4 x2 = base[(size_t)s2 * 256 + tid];
    const float4 x3 = base[(size_t)s3 * 256 + tid];
    acc.x += w0*x0.x + w1*x1.x + w2*x2.x + w3*x3.x;
    acc.y += w0*x0.y + w1*x1.y + w2*x2.y + w3*x3.y;
    acc.z += w0*x0.z + w1*x1.z + w2*x2.z + w3*x3.z;
    acc.w += w0*x0.w + w1*x1.w + w2*x2.w + w3*x3.w;
  }
  float* o = out + b * II + tid * 4;
  atomicAdd(o + 0, acc.x);
  atomicAdd(o + 1, acc.y);
  atomicAdd(o + 2, acc.z);
  atomicAdd(o + 3, acc.w);
}

extern "C" void kernel_launch(void* const* d_in, const int* in_sizes, int n_in,
                              void* d_out, int out_size, void* d_ws, size_t ws_size,
                              hipStream_t stream) {
  const float* queries = (const float*)d_in[0];
  const float* items   = (const float*)d_in[1];
  const int*   weights = (const int*)d_in[2];
  const float* W       = (const float*)d_in[3];
  const float* U       = (const float*)d_in[4];
  const float* v       = (const float*)d_in[5];
  float* out = (float*)d_out;

  char* ws = (char*)d_ws;
  unsigned short* Ut = (unsigned short*)ws;                         // 2 MB
  float* pq    = (float*)(ws + (2u << 20));                         // 128 KB
  float* react = (float*)(ws + (2u << 20) + (128u << 10));          // 256 KB
  const size_t bf_off = (2u << 20) + (128u << 10) + (256u << 10);
  unsigned short* Aswz = (unsigned short*)(ws + bf_off);            // 128 MB (path A)
  const bool pathA = ws_size >= bf_off + (size_t)MM * II * 2;

  hipMemsetAsync(pq, 0, BB * AA * sizeof(float), stream);
  hipMemsetAsync(react, 0, MM * sizeof(float), stream);
  hipMemsetAsync(out, 0, BB * II * sizeof(float), stream);

  k_transpose_u<<<dim3(16, 16), 256, 0, stream>>>(U, Ut);
  k_pq<<<dim3(8, 4), 256, 0, stream>>>(queries, W, pq);
  if (pathA) {
    k_conv_swz<<<dim3(4096), 256, 0, stream>>>(items, Aswz);
    k_gemm_bf<<<dim3(4096), 256, 0, stream>>>(Aswz, Ut, pq, v, react);
  } else {
    k_gemm_f32<<<dim3(4096), 256, 0, stream>>>(items, Ut, pq, v, react);
  }
  k_softmax<<<dim3(BB), 256, 0, stream>>>(react, weights, out + BB * II);
  k_blended<<<dim3(BB, 16), 256, 0, stream>>>(items, out + BB * II, out);
}